// Round 2
// baseline (90.535 us; speedup 1.0000x reference)
//
#include <hip/hip_runtime.h>
#include <hip/hip_bf16.h>

#define NMAX 2048
#define HH 128
#define WW 128
#define NBIN 16            // depth-value bins == segments
#define ZLO 3.0f
#define ZHI 9.0f
#define NEARP 0.1f
#define CULL_LOG_EPS -18.0f   // keep iff max-over-tile ln(op*exp(p)) > -18

// Runtime-adaptive input load: reference ships fp32; guard against a bf16
// dataset variant. Detected from intrinsics[0] (==150.0 iff fp32).
static __device__ __forceinline__ float ldin(const void* p, int i, bool is32) {
    return is32 ? ((const float*)p)[i]
                : __bfloat162float(((const __hip_bfloat16*)p)[i]);
}
static __device__ __forceinline__ bool detect32(const void* intr) {
    return ((const float*)intr)[0] > 1.0f;
}
static __device__ __forceinline__ void stout(void* out, int i, float v, bool is32) {
    if (is32) ((float*)out)[i] = v;
    else      ((__hip_bfloat16*)out)[i] = __float2bfloat16(v);
}

// Record layout (12 floats, 3x float4):
// [0]=u [1]=v [2]=na(=-0.5*cA) [3]=nb(=-cB) [4]=nc(=-0.5*cC)
// [5]=zc (camera depth; sort key value)
// [6]=cr [7]=cg [8]=cb
// [9]=qy = nc - nb^2/(4 na)   (max over dx of power at fixed dy)
// [10]=ln(op)                 (-inf for invalid/pad -> self-culling)
// [11]=qx = na - nb^2/(4 nc)
// pwr = na*dx^2 + nb*dx*dy + nc*dy^2 ; alpha = min(exp(min(pwr,0)+lnop), .99)

// ---------------------------------------------------------------- preprocess
__global__ __launch_bounds__(256) void gs_preprocess(
    const void* __restrict__ means,
    const void* __restrict__ log_scales,
    const void* __restrict__ rots,
    const void* __restrict__ colors,
    const void* __restrict__ opac,
    const void* __restrict__ intr,
    const void* __restrict__ c2w,
    int n,
    float* __restrict__ params)
{
    int i = blockIdx.x * blockDim.x + threadIdx.x;
    if (i >= NMAX) return;
    bool is32 = detect32(intr);
    float* p = params + i * 12;
    if (i >= n) {
        // benign self-culling record
        #pragma unroll
        for (int k = 0; k < 12; ++k) p[k] = 0.f;
        p[10] = -__builtin_inff();
        return;
    }

    // camera: Rwc = Rcw^T, twc = -Rwc @ tcw
    float Rwc[3][3], twc[3];
    {
        float Rcw[3][3], tcw[3];
        for (int r = 0; r < 3; ++r) {
            for (int c = 0; c < 3; ++c) Rcw[r][c] = ldin(c2w, r * 4 + c, is32);
            tcw[r] = ldin(c2w, r * 4 + 3, is32);
        }
        for (int r = 0; r < 3; ++r)
            for (int c = 0; c < 3; ++c) Rwc[r][c] = Rcw[c][r];
        for (int r = 0; r < 3; ++r)
            twc[r] = -(Rwc[r][0] * tcw[0] + Rwc[r][1] * tcw[1] + Rwc[r][2] * tcw[2]);
    }
    float fx = ldin(intr, 0, is32), fy = ldin(intr, 4, is32);
    float cx = ldin(intr, 2, is32), cy = ldin(intr, 5, is32);

    float mx = ldin(means, 3 * i, is32), my = ldin(means, 3 * i + 1, is32),
          mz = ldin(means, 3 * i + 2, is32);
    float px = Rwc[0][0] * mx + Rwc[0][1] * my + Rwc[0][2] * mz + twc[0];
    float py = Rwc[1][0] * mx + Rwc[1][1] * my + Rwc[1][2] * mz + twc[1];
    float pz = Rwc[2][0] * mx + Rwc[2][1] * my + Rwc[2][2] * mz + twc[2];
    bool valid = pz > NEARP;
    float zc = fmaxf(pz, NEARP);
    float izc = 1.0f / zc;
    float u = fx * px * izc + cx;
    float v = fy * py * izc + cy;

    // quaternion -> R
    float qw = ldin(rots, 4 * i, is32), qx = ldin(rots, 4 * i + 1, is32),
          qy = ldin(rots, 4 * i + 2, is32), qz = ldin(rots, 4 * i + 3, is32);
    float nrm = sqrtf(qw * qw + qx * qx + qy * qy + qz * qz);
    float inv = 1.0f / fmaxf(nrm, 1e-8f);
    qw *= inv; qx *= inv; qy *= inv; qz *= inv;
    float xx = qx * qx, yy = qy * qy, zz = qz * qz;
    float xy = qx * qy, xz = qx * qz, yz = qy * qz;
    float wx = qw * qx, wy = qw * qy, wz = qw * qz;
    float R[3][3] = {
        {1.f - 2.f * (yy + zz), 2.f * (xy - wz),       2.f * (xz + wy)},
        {2.f * (xy + wz),       1.f - 2.f * (xx + zz), 2.f * (yz - wx)},
        {2.f * (xz - wy),       2.f * (yz + wx),       1.f - 2.f * (xx + yy)}
    };
    float s2[3];
    for (int k = 0; k < 3; ++k) s2[k] = __expf(2.0f * ldin(log_scales, 3 * i + k, is32));

    // cov3d = R diag(s2) R^T + 1e-6 I
    float M[3][3];
    for (int r = 0; r < 3; ++r)
        for (int c = 0; c < 3; ++c)
            M[r][c] = R[r][0] * s2[0] * R[c][0] + R[r][1] * s2[1] * R[c][1]
                    + R[r][2] * s2[2] * R[c][2];
    M[0][0] += 1e-6f; M[1][1] += 1e-6f; M[2][2] += 1e-6f;

    // cov_cam = Rwc M Rwc^T
    float TM[3][3];
    for (int r = 0; r < 3; ++r)
        for (int c = 0; c < 3; ++c)
            TM[r][c] = Rwc[r][0] * M[0][c] + Rwc[r][1] * M[1][c] + Rwc[r][2] * M[2][c];
    float CC[3][3];
    for (int r = 0; r < 3; ++r)
        for (int c = 0; c < 3; ++c)
            CC[r][c] = TM[r][0] * Rwc[c][0] + TM[r][1] * Rwc[c][1] + TM[r][2] * Rwc[c][2];

    // J rows
    float J0[3] = {fx * izc, 0.0f, -fx * px * izc * izc};
    float J1[3] = {0.0f, fy * izc, -fy * py * izc * izc};
    float t0[3], t1[3];
    for (int c = 0; c < 3; ++c) {
        t0[c] = J0[0] * CC[0][c] + J0[1] * CC[1][c] + J0[2] * CC[2][c];
        t1[c] = J1[0] * CC[0][c] + J1[1] * CC[1][c] + J1[2] * CC[2][c];
    }
    float a  = t0[0] * J0[0] + t0[1] * J0[1] + t0[2] * J0[2] + 0.3f;
    float bq = t0[0] * J1[0] + t0[1] * J1[1] + t0[2] * J1[2];
    float cq = t1[0] * J1[0] + t1[1] * J1[1] + t1[2] * J1[2] + 0.3f;
    float det = fmaxf(a * cq - bq * bq, 1e-12f);
    float idet = 1.0f / det;
    float cA = cq * idet, cB = -bq * idet, cCc = a * idet;

    float o  = ldin(opac, i, is32);
    float op = valid ? (1.0f / (1.0f + __expf(-o))) : 0.0f;
    float cr = fminf(fmaxf(ldin(colors, 3 * i, is32), 0.f), 1.f);
    float cg = fminf(fmaxf(ldin(colors, 3 * i + 1, is32), 0.f), 1.f);
    float cb = fminf(fmaxf(ldin(colors, 3 * i + 2, is32), 0.f), 1.f);

    // conic coefficients for the power form p = na dx^2 + nb dx dy + nc dy^2
    float na  = -0.5f * cA;   // < 0 (conic negative-definite)
    float nb  = -cB;
    float ncc = -0.5f * cCc;  // < 0
    float qyb = ncc - nb * nb / (4.0f * na);   // <= 0
    float qxb = na  - nb * nb / (4.0f * ncc);  // <= 0
    float lnop = __logf(op);                   // -inf when op==0 (invalid)

    p[0] = u;  p[1] = v;
    p[2] = na;  p[3] = nb;  p[4] = ncc;
    p[5] = zc;
    p[6] = cr; p[7] = cg; p[8] = cb;
    p[9] = qyb; p[10] = lnop; p[11] = qxb;
}

// --------------------------- render: depth-binned, per-block cull+sort+blend
// Grid (32 tiles of 32x16 px, NBIN depth bins). Each block scans all NMAX
// records, keeps those whose depth-bin == blockIdx.y AND that pass the
// conservative tile cull, locally rank-sorts the survivors by the unique key
// (z_bits<<32)|index (== reference's stable depth argsort restricted to the
// survivors; bin assignment is monotone in z so bin concatenation preserves
// global order for ANY input), then composites 2 px/thread.
__global__ __launch_bounds__(256) void gs_render_binned(
    const float* __restrict__ params,
    float4* __restrict__ segbuf)
{
    __shared__ unsigned long long slist[NMAX];
    __shared__ int scnt;
    int t = threadIdx.x;
    int bin = blockIdx.y;
    int x0 = (blockIdx.x & 3) * 32;
    int y0 = (blockIdx.x >> 2) * 16;
    if (t == 0) scnt = 0;
    __syncthreads();

    const float kbin = (float)NBIN / (ZHI - ZLO);
    #pragma unroll
    for (int k = 0; k < NMAX / 256; ++k) {
        int g = k * 256 + t;
        const float4* rp = (const float4*)(params + 12 * g);
        float4 A = rp[0];   // u v na nb
        float4 B = rp[1];   // nc zc cr cg
        float4 C = rp[2];   // cb qy lnop qx
        int zb = (int)((B.y - ZLO) * kbin);
        zb = zb < 0 ? 0 : (zb > NBIN - 1 ? NBIN - 1 : zb);
        float dxm = fmaxf(fmaxf((float)x0 - A.x, A.x - (float)(x0 + 31)), 0.f);
        float dym = fmaxf(fmaxf((float)y0 - A.y, A.y - (float)(y0 + 15)), 0.f);
        float bound = fminf(C.y * dym * dym, C.w * dxm * dxm) + C.z;
        if (zb == bin && bound > CULL_LOG_EPS) {
            int s = atomicAdd(&scnt, 1);
            slist[s] = (((unsigned long long)__float_as_uint(B.y)) << 32)
                     | (unsigned int)g;
        }
    }
    __syncthreads();
    int M = scnt;

    // in-place rank sort (keys unique -> ranks are a permutation)
    unsigned long long kk[NMAX / 256]; int rr[NMAX / 256];
    #pragma unroll
    for (int q = 0; q < NMAX / 256; ++q) {
        int s = q * 256 + t;
        rr[q] = -1;
        if (s < M) {
            unsigned long long key = slist[s];
            int r = 0;
            for (int j = 0; j < M; ++j) r += (slist[j] < key) ? 1 : 0;
            kk[q] = key; rr[q] = r;
        }
    }
    __syncthreads();
    #pragma unroll
    for (int q = 0; q < NMAX / 256; ++q)
        if (rr[q] >= 0) slist[rr[q]] = kk[q];
    __syncthreads();

    // composite 2 adjacent columns per thread (records re-read from L2;
    // uniform address per iteration -> broadcast loads)
    int col = x0 + ((t & 15) << 1);
    int row = y0 + (t >> 4);
    float px0 = (float)col;
    float px1 = px0 + 1.0f;
    float py  = (float)row;
    int pid0 = row * WW + col;

    float T0 = 1.f, r0 = 0.f, g0 = 0.f, b0 = 0.f;
    float T1 = 1.f, r1 = 0.f, g1 = 0.f, b1 = 0.f;
    #pragma unroll 2
    for (int i = 0; i < M; ++i) {
        int g = (int)(unsigned int)slist[i];
        const float4* rp = (const float4*)(params + 12 * g);
        float4 A = rp[0];
        float4 B = rp[1];
        float4 C = rp[2];
        float dy    = py - A.y;
        float nbdy  = A.w * dy;
        float ncdy2 = (B.x * dy) * dy;
        float lnop  = C.z;

        float dx0 = px0 - A.x;
        float p0 = fmaf(fmaf(A.z, dx0, nbdy), dx0, ncdy2);
        float al0 = fminf(__expf(fminf(p0, 0.0f) + lnop), 0.99f);
        float w0 = al0 * T0;
        r0 = fmaf(w0, B.z, r0);
        g0 = fmaf(w0, B.w, g0);
        b0 = fmaf(w0, C.x, b0);
        T0 *= (1.0f - al0);

        float dx1 = px1 - A.x;
        float p1 = fmaf(fmaf(A.z, dx1, nbdy), dx1, ncdy2);
        float al1 = fminf(__expf(fminf(p1, 0.0f) + lnop), 0.99f);
        float w1 = al1 * T1;
        r1 = fmaf(w1, B.z, r1);
        g1 = fmaf(w1, B.w, g1);
        b1 = fmaf(w1, C.x, b1);
        T1 *= (1.0f - al1);
    }
    segbuf[bin * (HH * WW) + pid0]     = make_float4(r0, g0, b0, T0);
    segbuf[bin * (HH * WW) + pid0 + 1] = make_float4(r1, g1, b1, T1);
}

// ---------------------------------------------------------------- combine
__global__ __launch_bounds__(256) void gs_combine(
    const float4* __restrict__ segbuf,
    void* __restrict__ out,
    const void* __restrict__ intr)
{
    int pid = blockIdx.x * 256 + threadIdx.x;
    if (pid >= HH * WW) return;
    bool is32 = detect32(intr);
    float r = 0.f, g = 0.f, b = 0.f, T = 1.0f;
    #pragma unroll
    for (int s = 0; s < NBIN; ++s) {
        float4 vv = segbuf[s * (HH * WW) + pid];
        r = fmaf(T, vv.x, r);
        g = fmaf(T, vv.y, g);
        b = fmaf(T, vv.z, b);
        T *= vv.w;
    }
    stout(out, pid * 3 + 0, r, is32);
    stout(out, pid * 3 + 1, g, is32);
    stout(out, pid * 3 + 2, b, is32);
}

// ------------- fallback (tiny workspace): per-tile full scan + sort + blend
__global__ __launch_bounds__(256) void gs_render_all(
    const float* __restrict__ params,
    void* __restrict__ out,
    const void* __restrict__ intr)
{
    __shared__ unsigned long long slist[NMAX];
    __shared__ int scnt;
    int t = threadIdx.x;
    int x0 = (blockIdx.x & 7) * 16;
    int y0 = (blockIdx.x >> 3) * 16;
    bool is32 = detect32(intr);
    if (t == 0) scnt = 0;
    __syncthreads();

    #pragma unroll
    for (int k = 0; k < NMAX / 256; ++k) {
        int g = k * 256 + t;
        const float4* rp = (const float4*)(params + 12 * g);
        float4 A = rp[0]; float4 B = rp[1]; float4 C = rp[2];
        float dxm = fmaxf(fmaxf((float)x0 - A.x, A.x - (float)(x0 + 15)), 0.f);
        float dym = fmaxf(fmaxf((float)y0 - A.y, A.y - (float)(y0 + 15)), 0.f);
        float bound = fminf(C.y * dym * dym, C.w * dxm * dxm) + C.z;
        if (bound > CULL_LOG_EPS) {
            int s = atomicAdd(&scnt, 1);
            slist[s] = (((unsigned long long)__float_as_uint(B.y)) << 32)
                     | (unsigned int)g;
        }
    }
    __syncthreads();
    int M = scnt;
    unsigned long long kk[NMAX / 256]; int rr[NMAX / 256];
    #pragma unroll
    for (int q = 0; q < NMAX / 256; ++q) {
        int s = q * 256 + t;
        rr[q] = -1;
        if (s < M) {
            unsigned long long key = slist[s];
            int r = 0;
            for (int j = 0; j < M; ++j) r += (slist[j] < key) ? 1 : 0;
            kk[q] = key; rr[q] = r;
        }
    }
    __syncthreads();
    #pragma unroll
    for (int q = 0; q < NMAX / 256; ++q)
        if (rr[q] >= 0) slist[rr[q]] = kk[q];
    __syncthreads();

    float pxf = (float)(x0 + (t & 15));
    float pyf = (float)(y0 + (t >> 4));
    float T = 1.f, r = 0.f, g = 0.f, b = 0.f;
    for (int i = 0; i < M; ++i) {
        int gg = (int)(unsigned int)slist[i];
        const float4* rp = (const float4*)(params + 12 * gg);
        float4 A = rp[0]; float4 B = rp[1]; float4 C = rp[2];
        float dx = pxf - A.x;
        float dy = pyf - A.y;
        float pwr = fmaf(fmaf(A.z, dx, A.w * dy), dx, (B.x * dy) * dy);
        float alpha = fminf(__expf(fminf(pwr, 0.0f) + C.z), 0.99f);
        float wgt = alpha * T;
        r = fmaf(wgt, B.z, r);
        g = fmaf(wgt, B.w, g);
        b = fmaf(wgt, C.x, b);
        T *= (1.0f - alpha);
    }
    int pid = (y0 + (t >> 4)) * WW + x0 + (t & 15);
    stout(out, pid * 3 + 0, r, is32);
    stout(out, pid * 3 + 1, g, is32);
    stout(out, pid * 3 + 2, b, is32);
}

extern "C" void kernel_launch(void* const* d_in, const int* in_sizes, int n_in,
                              void* d_out, int out_size, void* d_ws, size_t ws_size,
                              hipStream_t stream)
{
    const void* means      = d_in[0];
    const void* log_scales = d_in[1];
    const void* rotations  = d_in[2];
    const void* colors     = d_in[3];
    const void* opacities  = d_in[4];
    const void* intrinsics = d_in[5];
    const void* cam2world  = d_in[6];

    int n = in_sizes[4];
    if (n > NMAX) n = NMAX;

    // workspace layout
    size_t off_params = 0;                       // 96 KB
    size_t off_seg    = NMAX * 48;               // 4 MB segment buffer
    size_t need_seg   = off_seg + (size_t)NBIN * HH * WW * 16;

    float* params  = (float*)((char*)d_ws + off_params);
    float4* segbuf = (float4*)((char*)d_ws + off_seg);

    gs_preprocess<<<NMAX / 256, 256, 0, stream>>>(
        means, log_scales, rotations, colors, opacities, intrinsics, cam2world,
        n, params);

    if (ws_size >= need_seg) {
        dim3 rg(32, NBIN);   // 32x16-px tiles x depth bins
        gs_render_binned<<<rg, 256, 0, stream>>>(params, segbuf);
        gs_combine<<<HH * WW / 256, 256, 0, stream>>>(segbuf, d_out, intrinsics);
    } else {
        gs_render_all<<<HH * WW / 256, 256, 0, stream>>>(params, d_out, intrinsics);
    }
}